// Round 1
// baseline (2155.088 us; speedup 1.0000x reference)
//
#include <hip/hip_runtime.h>
#include <math.h>

// Problem constants
#define B_   4
#define S_   2048
#define D_   1024
#define H_   1024
#define NROW 2048                  // attention row length (= S_)
#define TOTX 8388608.0f            // B_*S_*D_ elements of x

// ---------------------------------------------------------------------------
// abs-sum reduction for sparsity = mean(|x|)
// ---------------------------------------------------------------------------
__global__ __launch_bounds__(256) void abs_sum_kernel(const float* __restrict__ x,
                                                      long long n4, float* out) {
  long long i0 = (long long)blockIdx.x * blockDim.x + threadIdx.x;
  long long stride = (long long)gridDim.x * blockDim.x;
  float s = 0.f;
  const float4* x4 = (const float4*)x;
  for (long long i = i0; i < n4; i += stride) {
    float4 v = x4[i];
    s += fabsf(v.x) + fabsf(v.y) + fabsf(v.z) + fabsf(v.w);
  }
#pragma unroll
  for (int off = 32; off; off >>= 1) s += __shfl_xor(s, off);
  __shared__ float red[4];
  if ((threadIdx.x & 63) == 0) red[threadIdx.x >> 6] = s;
  __syncthreads();
  if (threadIdx.x == 0) atomicAdd(out, red[0] + red[1] + red[2] + red[3]);
}

// ---------------------------------------------------------------------------
// GEMM NT: C[m,n] = scale * sum_k A[m,k] * B[n,k]   (A: MxK rm, B: NxK rm)
// 64x64 tile, BK=16, 256 threads, 4x4 per thread.
// ---------------------------------------------------------------------------
__global__ __launch_bounds__(256) void gemm_nt(const float* __restrict__ A,
                                               const float* __restrict__ Bm,
                                               float* __restrict__ C,
                                               int M, int N, int K,
                                               long long sA, long long sB, long long sC,
                                               float scale) {
  const int b = blockIdx.z;
  A  += (long long)b * sA;
  Bm += (long long)b * sB;
  C  += (long long)b * sC;

  __shared__ float As[16][68];   // [k][m], +4 pad keeps float4 alignment, kills conflicts
  __shared__ float Bs[16][68];   // [k][n]

  const int tid = threadIdx.x;
  const int tx = tid & 15, ty = tid >> 4;
  const int m0 = blockIdx.y * 64, n0 = blockIdx.x * 64;

  float acc[4][4] = {};

  const int lk = tid & 15;
  const int lmBase = tid >> 4;

  for (int k0 = 0; k0 < K; k0 += 16) {
#pragma unroll
    for (int it = 0; it < 4; ++it) {
      int lm = lmBase + it * 16;
      As[lk][lm] = A[(long long)(m0 + lm) * K + k0 + lk];
      Bs[lk][lm] = Bm[(long long)(n0 + lm) * K + k0 + lk];
    }
    __syncthreads();
#pragma unroll
    for (int kk = 0; kk < 16; ++kk) {
      float4 a4 = *(const float4*)&As[kk][ty * 4];
      float4 b4 = *(const float4*)&Bs[kk][tx * 4];
      float a[4] = {a4.x, a4.y, a4.z, a4.w};
      float bb[4] = {b4.x, b4.y, b4.z, b4.w};
#pragma unroll
      for (int i = 0; i < 4; ++i)
#pragma unroll
        for (int j = 0; j < 4; ++j) acc[i][j] = fmaf(a[i], bb[j], acc[i][j]);
    }
    __syncthreads();
  }

#pragma unroll
  for (int i = 0; i < 4; ++i) {
    int m = m0 + ty * 4 + i;
    float4 o = make_float4(acc[i][0] * scale, acc[i][1] * scale,
                           acc[i][2] * scale, acc[i][3] * scale);
    *(float4*)&C[(long long)m * N + n0 + tx * 4] = o;
  }
}

// ---------------------------------------------------------------------------
// GEMM NN: C[m,n] = sum_k A[m,k] * B[k,n]   (A: MxK rm, B: KxN rm)
// ---------------------------------------------------------------------------
__global__ __launch_bounds__(256) void gemm_nn(const float* __restrict__ A,
                                               const float* __restrict__ Bm,
                                               float* __restrict__ C,
                                               int M, int N, int K,
                                               long long sA, long long sB, long long sC) {
  const int b = blockIdx.z;
  A  += (long long)b * sA;
  Bm += (long long)b * sB;
  C  += (long long)b * sC;

  __shared__ float As[16][68];
  __shared__ float Bs[16][68];

  const int tid = threadIdx.x;
  const int tx = tid & 15, ty = tid >> 4;
  const int m0 = blockIdx.y * 64, n0 = blockIdx.x * 64;

  float acc[4][4] = {};

  const int lkA = tid & 15;
  const int lmBase = tid >> 4;
  const int lnB = tid & 63;
  const int lkBBase = tid >> 6;

  for (int k0 = 0; k0 < K; k0 += 16) {
#pragma unroll
    for (int it = 0; it < 4; ++it) {
      int lm = lmBase + it * 16;
      As[lkA][lm] = A[(long long)(m0 + lm) * K + k0 + lkA];
    }
#pragma unroll
    for (int it = 0; it < 4; ++it) {
      int lkB = lkBBase + it * 4;
      Bs[lkB][lnB] = Bm[(long long)(k0 + lkB) * N + n0 + lnB];
    }
    __syncthreads();
#pragma unroll
    for (int kk = 0; kk < 16; ++kk) {
      float4 a4 = *(const float4*)&As[kk][ty * 4];
      float4 b4 = *(const float4*)&Bs[kk][tx * 4];
      float a[4] = {a4.x, a4.y, a4.z, a4.w};
      float bb[4] = {b4.x, b4.y, b4.z, b4.w};
#pragma unroll
      for (int i = 0; i < 4; ++i)
#pragma unroll
        for (int j = 0; j < 4; ++j) acc[i][j] = fmaf(a[i], bb[j], acc[i][j]);
    }
    __syncthreads();
  }

#pragma unroll
  for (int i = 0; i < 4; ++i) {
    int m = m0 + ty * 4 + i;
    float4 o = make_float4(acc[i][0], acc[i][1], acc[i][2], acc[i][3]);
    *(float4*)&C[(long long)m * N + n0 + tx * 4] = o;
  }
}

// ---------------------------------------------------------------------------
// Row-wise sparsemax (faithful port, incl. nonstandard per-position tau)
// or softmax, selected by on-device sparsity flag. One block per row.
// ---------------------------------------------------------------------------
__global__ __launch_bounds__(256) void attn_row_kernel(float* __restrict__ scores,
                                                       const float* __restrict__ absSum) {
  __shared__ float z[NROW];      // z in original order
  __shared__ float cs[NROW];     // sorted, then cumsum
  __shared__ float part[256];
  __shared__ float red4[4];

  const int tid = threadIdx.x;
  float* rowp = scores + (long long)blockIdx.x * NROW;

  for (int i = tid; i < NROW; i += 256) z[i] = rowp[i];
  __syncthreads();

  // row max
  float lm = -INFINITY;
  for (int i = tid; i < NROW; i += 256) lm = fmaxf(lm, z[i]);
#pragma unroll
  for (int off = 32; off; off >>= 1) lm = fmaxf(lm, __shfl_xor(lm, off));
  if ((tid & 63) == 0) red4[tid >> 6] = lm;
  __syncthreads();
  const float rowmax = fmaxf(fmaxf(red4[0], red4[1]), fmaxf(red4[2], red4[3]));
  __syncthreads();

  const bool use_softmax = (absSum[0] * (1.0f / TOTX)) >= 1.0f;

  if (use_softmax) {
    float ls = 0.f;
    for (int i = tid; i < NROW; i += 256) {
      float e = expf(z[i] - rowmax);
      z[i] = e;
      ls += e;
    }
#pragma unroll
    for (int off = 32; off; off >>= 1) ls += __shfl_xor(ls, off);
    if ((tid & 63) == 0) red4[tid >> 6] = ls;
    __syncthreads();
    float s = red4[0] + red4[1] + red4[2] + red4[3];
    float inv = 1.0f / s;
    for (int i = tid; i < NROW; i += 256) rowp[i] = z[i] * inv;
    return;
  }

  // ---- sparsemax ----
  float lsum = 0.f;
  for (int i = tid; i < NROW; i += 256) {
    float zz = z[i] - rowmax;
    z[i] = zz;
    cs[i] = zz;
    lsum += zz;
  }
#pragma unroll
  for (int off = 32; off; off >>= 1) lsum += __shfl_xor(lsum, off);
  if ((tid & 63) == 0) red4[tid >> 6] = lsum;
  __syncthreads();
  const float sum_z = red4[0] + red4[1] + red4[2] + red4[3];
  const float step = (sum_z - 1.0f) * (1.0f / (float)NROW);
  __syncthreads();

  // bitonic sort cs[] DESCENDING (classic xor-network, directions inverted)
  for (int k = 2; k <= NROW; k <<= 1) {
    for (int j = k >> 1; j > 0; j >>= 1) {
      for (int i = tid; i < NROW; i += 256) {
        int ixj = i ^ j;
        if (ixj > i) {
          float a = cs[i], b = cs[ixj];
          bool desc = ((i & k) == 0);
          if (desc ? (a < b) : (a > b)) { cs[i] = b; cs[ixj] = a; }
        }
      }
      __syncthreads();
    }
  }

  // k = count(sorted_z > step) -- valid: descending sort makes is_gt a prefix
  float lcnt = 0.f;
  for (int i = tid; i < NROW; i += 256) lcnt += (cs[i] > step) ? 1.0f : 0.0f;
#pragma unroll
  for (int off = 32; off; off >>= 1) lcnt += __shfl_xor(lcnt, off);
  if ((tid & 63) == 0) red4[tid >> 6] = lcnt;
  __syncthreads();
  const float kf = red4[0] + red4[1] + red4[2] + red4[3];
  __syncthreads();

  // inclusive cumsum of cs[] in place (8-per-thread chunks + block scan)
  float chunk[8];
  const int base = tid * 8;
  {
    float run = 0.f;
#pragma unroll
    for (int i2 = 0; i2 < 8; ++i2) { run += cs[base + i2]; chunk[i2] = run; }
    part[tid] = run;
  }
  __syncthreads();
#pragma unroll
  for (int off = 1; off < 256; off <<= 1) {
    float v = (tid >= off) ? part[tid - off] : 0.f;
    __syncthreads();
    part[tid] += v;
    __syncthreads();
  }
  const float pofs = (tid > 0) ? part[tid - 1] : 0.f;

  const float inv_k = 1.0f / kf;
  const float c1 = 1.0f + step * kf;   // tau_j = (cumsum_j - 1 - step*k)/k
#pragma unroll
  for (int i2 = 0; i2 < 8; ++i2) {
    int jj = base + i2;
    float tau = (chunk[i2] + pofs - c1) * inv_k;
    rowp[jj] = fmaxf(z[jj] - tau, 0.0f);
  }
}

// ---------------------------------------------------------------------------
extern "C" void kernel_launch(void* const* d_in, const int* in_sizes, int n_in,
                              void* d_out, int out_size, void* d_ws, size_t ws_size,
                              hipStream_t stream) {
  const float* x  = (const float*)d_in[0];
  const float* Wq = (const float*)d_in[1];
  const float* Wk = (const float*)d_in[2];
  const float* Wv = (const float*)d_in[3];
  float* out = (float*)d_out;

  // workspace layout (floats)
  float* ws = (float*)d_ws;
  const long long MD = (long long)B_ * S_ * H_;        // 8M elems per projection
  float* Q    = ws;
  float* Kp   = ws + MD;
  float* V    = ws + 2 * MD;
  float* Sc   = ws + 3 * MD;                           // B*S*S = 16M elems
  float* flag = ws + 3 * MD + (long long)B_ * S_ * S_; // 1 elem

  hipMemsetAsync(flag, 0, sizeof(float), stream);

  // sparsity = mean(|x|)
  abs_sum_kernel<<<512, 256, 0, stream>>>(x, (long long)(B_ * S_ * D_) / 4, flag);

  // Projections: Q/K/V = x @ W^T   (M=8192, N=1024, K=1024)
  {
    dim3 grid(H_ / 64, (B_ * S_) / 64, 1);
    gemm_nt<<<grid, 256, 0, stream>>>(x, Wq, Q, B_ * S_, H_, D_, 0, 0, 0, 1.0f);
    gemm_nt<<<grid, 256, 0, stream>>>(x, Wk, Kp, B_ * S_, H_, D_, 0, 0, 0, 1.0f);
    gemm_nt<<<grid, 256, 0, stream>>>(x, Wv, V, B_ * S_, H_, D_, 0, 0, 0, 1.0f);
  }

  // scores = Q @ K^T / 32  (batched; M=N=2048, K=1024)
  {
    dim3 grid(S_ / 64, S_ / 64, B_);
    gemm_nt<<<grid, 256, 0, stream>>>(Q, Kp, Sc, S_, S_, H_,
                                      (long long)S_ * H_, (long long)S_ * H_,
                                      (long long)S_ * S_, 1.0f / 32.0f);
  }

  // attention = sparsemax-or-softmax(scores), row-wise in place
  attn_row_kernel<<<B_ * S_, 256, 0, stream>>>(Sc, flag);

  // out = attention @ V  (batched; M=2048, N=1024, K=2048)
  {
    dim3 grid(H_ / 64, S_ / 64, B_);
    gemm_nn<<<grid, 256, 0, stream>>>(Sc, V, out, S_, H_, S_,
                                      (long long)S_ * S_, (long long)S_ * H_,
                                      (long long)S_ * H_);
  }
}

// Round 4
// 919.639 us; speedup vs baseline: 2.3434x; 2.3434x over previous
//
#include <hip/hip_runtime.h>
#include <math.h>

// Problem constants
#define B_   4
#define S_   2048
#define D_   1024
#define H_   1024
#define NROW 2048
#define TOTX 8388608.0f            // B_*S_*D_ elements of x

typedef short bf16x8 __attribute__((ext_vector_type(8)));
typedef unsigned short u16x8 __attribute__((ext_vector_type(8)));
typedef float f32x4 __attribute__((ext_vector_type(4)));

__device__ __forceinline__ unsigned short f2bf(float f) {
  unsigned int u = __float_as_uint(f);
  unsigned int r = u + 0x7fffu + ((u >> 16) & 1u);   // RNE
  return (unsigned short)(r >> 16);
}
__device__ __forceinline__ float bf2f(unsigned short h) {
  return __uint_as_float(((unsigned int)h) << 16);
}
// pack x into hi/lo bf16 pair: hi = bf16(x), lo = bf16(x - hi)
__device__ __forceinline__ unsigned int packsplit(float v) {
  unsigned short h = f2bf(v);
  unsigned short l = f2bf(v - bf2f(h));
  return (((unsigned int)h) << 16) | l;
}

// ---------------------------------------------------------------------------
// abs-sum reduction for sparsity = mean(|x|)
// ---------------------------------------------------------------------------
__global__ __launch_bounds__(256) void abs_sum_kernel(const float* __restrict__ x,
                                                      long long n4, float* out) {
  long long i0 = (long long)blockIdx.x * blockDim.x + threadIdx.x;
  long long stride = (long long)gridDim.x * blockDim.x;
  float s = 0.f;
  const float4* x4 = (const float4*)x;
  for (long long i = i0; i < n4; i += stride) {
    float4 v = x4[i];
    s += fabsf(v.x) + fabsf(v.y) + fabsf(v.z) + fabsf(v.w);
  }
#pragma unroll
  for (int off = 32; off; off >>= 1) s += __shfl_xor(s, off);
  __shared__ float red[4];
  if ((threadIdx.x & 63) == 0) red[threadIdx.x >> 6] = s;
  __syncthreads();
  if (threadIdx.x == 0) atomicAdd(out, red[0] + red[1] + red[2] + red[3]);
}

// ---------------------------------------------------------------------------
// float -> plain bf16
// ---------------------------------------------------------------------------
__global__ __launch_bounds__(256) void f2bf_kernel(const float* __restrict__ in,
                                                   unsigned short* __restrict__ out,
                                                   int n4) {
  int i = blockIdx.x * 256 + threadIdx.x;
  if (i >= n4) return;
  float4 v = ((const float4*)in)[i];
  ushort4 o;
  o.x = f2bf(v.x); o.y = f2bf(v.y); o.z = f2bf(v.z); o.w = f2bf(v.w);
  ((ushort4*)out)[i] = o;
}

// ---------------------------------------------------------------------------
// float -> packed split bf16 pair (hi<<16 | lo)
// ---------------------------------------------------------------------------
__global__ __launch_bounds__(256) void pack_split_kernel(const float* __restrict__ in,
                                                         unsigned int* __restrict__ out,
                                                         int n4) {
  int i = blockIdx.x * 256 + threadIdx.x;
  if (i >= n4) return;
  float4 v = ((const float4*)in)[i];
  uint4 o;
  o.x = packsplit(v.x); o.y = packsplit(v.y); o.z = packsplit(v.z); o.w = packsplit(v.w);
  ((uint4*)out)[i] = o;
}

// ---------------------------------------------------------------------------
// bf16 transpose per batch: in [R][C] -> out [C][R]
// ---------------------------------------------------------------------------
__global__ __launch_bounds__(256) void transpose_bf16(const unsigned short* __restrict__ in,
                                                      unsigned short* __restrict__ out,
                                                      int R, int C) {
  __shared__ unsigned short t[32][33];
  const int z = blockIdx.z;
  in  += (long long)z * R * C;
  out += (long long)z * R * C;
  const int c0 = blockIdx.x * 32, r0 = blockIdx.y * 32;
#pragma unroll
  for (int i = 0; i < 4; ++i) {
    int r = threadIdx.y + i * 8;
    t[r][threadIdx.x] = in[(long long)(r0 + r) * C + c0 + threadIdx.x];
  }
  __syncthreads();
#pragma unroll
  for (int i = 0; i < 4; ++i) {
    int r = threadIdx.y + i * 8;
    out[(long long)(c0 + r) * R + r0 + threadIdx.x] = t[threadIdx.x][r];
  }
}

// ---------------------------------------------------------------------------
// PLAIN bf16 MFMA GEMM NT (for V projection and PV): C = scale * A B^T
// ---------------------------------------------------------------------------
template <bool OUT_BF16>
__global__ __launch_bounds__(256) void gemm_nt_mfma(const unsigned short* __restrict__ A,
                                                    const unsigned short* __restrict__ B,
                                                    void* __restrict__ Cv,
                                                    int M, int N, int K,
                                                    long long sA, long long sB, long long sC,
                                                    float scale) {
  const int bz = blockIdx.z;
  A += (long long)bz * sA;
  B += (long long)bz * sB;

  __shared__ __align__(16) unsigned short As[128][40];
  __shared__ __align__(16) unsigned short Bs[128][40];

  const int tid = threadIdx.x;
  const int lane = tid & 63;
  const int w = tid >> 6;
  const int wm = (w & 1) << 6;
  const int wn = (w >> 1) << 6;
  const int m0 = blockIdx.y * 128, n0 = blockIdx.x * 128;

  f32x4 acc[4][4] = {};

  const int r0 = tid >> 2;
  const int kq = (tid & 3) * 8;
  const int fm = lane & 15;
  const int fk = (lane >> 4) * 8;

  for (int k0 = 0; k0 < K; k0 += 32) {
    uint4 a0 = *(const uint4*)(A + (long long)(m0 + r0) * K + k0 + kq);
    uint4 a1 = *(const uint4*)(A + (long long)(m0 + r0 + 64) * K + k0 + kq);
    uint4 b0 = *(const uint4*)(B + (long long)(n0 + r0) * K + k0 + kq);
    uint4 b1 = *(const uint4*)(B + (long long)(n0 + r0 + 64) * K + k0 + kq);
    *(uint4*)&As[r0][kq]      = a0;
    *(uint4*)&As[r0 + 64][kq] = a1;
    *(uint4*)&Bs[r0][kq]      = b0;
    *(uint4*)&Bs[r0 + 64][kq] = b1;
    __syncthreads();

    bf16x8 af[4], bfr[4];
#pragma unroll
    for (int mi = 0; mi < 4; ++mi)
      af[mi] = *(const bf16x8*)&As[wm + mi * 16 + fm][fk];
#pragma unroll
    for (int ni = 0; ni < 4; ++ni)
      bfr[ni] = *(const bf16x8*)&Bs[wn + ni * 16 + fm][fk];
#pragma unroll
    for (int mi = 0; mi < 4; ++mi)
#pragma unroll
      for (int ni = 0; ni < 4; ++ni)
        acc[mi][ni] = __builtin_amdgcn_mfma_f32_16x16x32_bf16(af[mi], bfr[ni],
                                                              acc[mi][ni], 0, 0, 0);
    __syncthreads();
  }

  const int cm = (lane >> 4) * 4;
  const int cn = lane & 15;
#pragma unroll
  for (int mi = 0; mi < 4; ++mi)
#pragma unroll
    for (int ni = 0; ni < 4; ++ni) {
#pragma unroll
      for (int r = 0; r < 4; ++r) {
        long long m = m0 + wm + mi * 16 + cm + r;
        long long n = n0 + wn + ni * 16 + cn;
        float v = acc[mi][ni][r] * scale;
        if (OUT_BF16)
          ((unsigned short*)Cv)[(long long)bz * sC + m * N + n] = f2bf(v);
        else
          ((float*)Cv)[(long long)bz * sC + m * N + n] = v;
      }
    }
}

// ---------------------------------------------------------------------------
// SPLIT bf16 MFMA GEMM NT: inputs are packed (hi<<16|lo) per element.
// C = scale * A B^T  computed as ah*bh + ah*bl + al*bh  (~fp32 accuracy).
// OUT_MODE: 0 = fp32, 2 = packed split.
// ---------------------------------------------------------------------------
template <int OUT_MODE>
__global__ __launch_bounds__(256) void gemm_nt_split(const unsigned int* __restrict__ A,
                                                     const unsigned int* __restrict__ B,
                                                     void* __restrict__ Cv,
                                                     int M, int N, int K,
                                                     long long sA, long long sB, long long sC,
                                                     float scale) {
  const int bz = blockIdx.z;
  A += (long long)bz * sA;
  B += (long long)bz * sB;

  __shared__ __align__(16) unsigned short As_h[128][40];
  __shared__ __align__(16) unsigned short As_l[128][40];
  __shared__ __align__(16) unsigned short Bs_h[128][40];
  __shared__ __align__(16) unsigned short Bs_l[128][40];

  const int tid = threadIdx.x;
  const int lane = tid & 63;
  const int w = tid >> 6;
  const int wm = (w & 1) << 6;
  const int wn = (w >> 1) << 6;
  const int m0 = blockIdx.y * 128, n0 = blockIdx.x * 128;

  f32x4 acc[4][4] = {};

  const int r0 = tid >> 2;
  const int kq = (tid & 3) * 8;      // element index within BK=32
  const int fm = lane & 15;
  const int fk = (lane >> 4) * 8;

  for (int k0 = 0; k0 < K; k0 += 32) {
#pragma unroll
    for (int half = 0; half < 2; ++half) {
      int rr = r0 + half * 64;
      const unsigned int* pa = A + (long long)(m0 + rr) * K + k0 + kq;
      const unsigned int* pb = B + (long long)(n0 + rr) * K + k0 + kq;
      uint4 a0 = *(const uint4*)pa;
      uint4 a1 = *(const uint4*)(pa + 4);
      uint4 b0 = *(const uint4*)pb;
      uint4 b1 = *(const uint4*)(pb + 4);
      u16x8 h, l;
      unsigned int ua[8] = {a0.x, a0.y, a0.z, a0.w, a1.x, a1.y, a1.z, a1.w};
#pragma unroll
      for (int j = 0; j < 8; ++j) { h[j] = (unsigned short)(ua[j] >> 16); l[j] = (unsigned short)ua[j]; }
      *(u16x8*)&As_h[rr][kq] = h;
      *(u16x8*)&As_l[rr][kq] = l;
      unsigned int ub[8] = {b0.x, b0.y, b0.z, b0.w, b1.x, b1.y, b1.z, b1.w};
#pragma unroll
      for (int j = 0; j < 8; ++j) { h[j] = (unsigned short)(ub[j] >> 16); l[j] = (unsigned short)ub[j]; }
      *(u16x8*)&Bs_h[rr][kq] = h;
      *(u16x8*)&Bs_l[rr][kq] = l;
    }
    __syncthreads();

    bf16x8 ah[4], al[4], bh[4], bl[4];
#pragma unroll
    for (int mi = 0; mi < 4; ++mi) {
      ah[mi] = *(const bf16x8*)&As_h[wm + mi * 16 + fm][fk];
      al[mi] = *(const bf16x8*)&As_l[wm + mi * 16 + fm][fk];
    }
#pragma unroll
    for (int ni = 0; ni < 4; ++ni) {
      bh[ni] = *(const bf16x8*)&Bs_h[wn + ni * 16 + fm][fk];
      bl[ni] = *(const bf16x8*)&Bs_l[wn + ni * 16 + fm][fk];
    }
#pragma unroll
    for (int mi = 0; mi < 4; ++mi)
#pragma unroll
      for (int ni = 0; ni < 4; ++ni) {
        acc[mi][ni] = __builtin_amdgcn_mfma_f32_16x16x32_bf16(al[mi], bh[ni], acc[mi][ni], 0, 0, 0);
        acc[mi][ni] = __builtin_amdgcn_mfma_f32_16x16x32_bf16(ah[mi], bl[ni], acc[mi][ni], 0, 0, 0);
        acc[mi][ni] = __builtin_amdgcn_mfma_f32_16x16x32_bf16(ah[mi], bh[ni], acc[mi][ni], 0, 0, 0);
      }
    __syncthreads();
  }

  const int cm = (lane >> 4) * 4;
  const int cn = lane & 15;
#pragma unroll
  for (int mi = 0; mi < 4; ++mi)
#pragma unroll
    for (int ni = 0; ni < 4; ++ni) {
#pragma unroll
      for (int r = 0; r < 4; ++r) {
        long long m = m0 + wm + mi * 16 + cm + r;
        long long n = n0 + wn + ni * 16 + cn;
        float v = acc[mi][ni][r] * scale;
        if (OUT_MODE == 0)
          ((float*)Cv)[(long long)bz * sC + m * N + n] = v;
        else
          ((unsigned int*)Cv)[(long long)bz * sC + m * N + n] = packsplit(v);
      }
    }
}

// ---------------------------------------------------------------------------
// Row-wise sparsemax (faithful port) or softmax; fp32 scores in, bf16 out.
// ---------------------------------------------------------------------------
__global__ __launch_bounds__(256) void attn_row_kernel(const float* __restrict__ scores,
                                                       unsigned short* __restrict__ attn,
                                                       const float* __restrict__ absSum) {
  __shared__ float z[NROW];
  __shared__ float cs[NROW];
  __shared__ float part[256];
  __shared__ float red4[4];

  const int tid = threadIdx.x;
  const float* rowp = scores + (long long)blockIdx.x * NROW;
  unsigned short* aout = attn + (long long)blockIdx.x * NROW;

  for (int i = tid; i < NROW; i += 256) z[i] = rowp[i];
  __syncthreads();

  float lm = -INFINITY;
  for (int i = tid; i < NROW; i += 256) lm = fmaxf(lm, z[i]);
#pragma unroll
  for (int off = 32; off; off >>= 1) lm = fmaxf(lm, __shfl_xor(lm, off));
  if ((tid & 63) == 0) red4[tid >> 6] = lm;
  __syncthreads();
  const float rowmax = fmaxf(fmaxf(red4[0], red4[1]), fmaxf(red4[2], red4[3]));
  __syncthreads();

  const bool use_softmax = (absSum[0] * (1.0f / TOTX)) >= 1.0f;

  if (use_softmax) {
    float ls = 0.f;
    for (int i = tid; i < NROW; i += 256) {
      float e = expf(z[i] - rowmax);
      z[i] = e;
      ls += e;
    }
#pragma unroll
    for (int off = 32; off; off >>= 1) ls += __shfl_xor(ls, off);
    if ((tid & 63) == 0) red4[tid >> 6] = ls;
    __syncthreads();
    float s = red4[0] + red4[1] + red4[2] + red4[3];
    float inv = 1.0f / s;
    for (int i = tid; i < NROW; i += 256) aout[i] = f2bf(z[i] * inv);
    return;
  }

  // ---- sparsemax ----
  float lsum = 0.f;
  for (int i = tid; i < NROW; i += 256) {
    float zz = z[i] - rowmax;
    z[i] = zz;
    cs[i] = zz;
    lsum += zz;
  }
#pragma unroll
  for (int off = 32; off; off >>= 1) lsum += __shfl_xor(lsum, off);
  if ((tid & 63) == 0) red4[tid >> 6] = lsum;
  __syncthreads();
  const float sum_z = red4[0] + red4[1] + red4[2] + red4[3];
  const float step = (sum_z - 1.0f) * (1.0f / (float)NROW);
  __syncthreads();

  // bitonic sort cs[] descending
  for (int k = 2; k <= NROW; k <<= 1) {
    for (int j = k >> 1; j > 0; j >>= 1) {
      for (int i = tid; i < NROW; i += 256) {
        int ixj = i ^ j;
        if (ixj > i) {
          float a = cs[i], b = cs[ixj];
          bool desc = ((i & k) == 0);
          if (desc ? (a < b) : (a > b)) { cs[i] = b; cs[ixj] = a; }
        }
      }
      __syncthreads();
    }
  }

  // k = count(sorted_z > step)
  float lcnt = 0.f;
  for (int i = tid; i < NROW; i += 256) lcnt += (cs[i] > step) ? 1.0f : 0.0f;
#pragma unroll
  for (int off = 32; off; off >>= 1) lcnt += __shfl_xor(lcnt, off);
  if ((tid & 63) == 0) red4[tid >> 6] = lcnt;
  __syncthreads();
  const float kf = red4[0] + red4[1] + red4[2] + red4[3];
  __syncthreads();

  // inclusive cumsum of cs[]
  float chunk[8];
  const int base = tid * 8;
  {
    float run = 0.f;
#pragma unroll
    for (int i2 = 0; i2 < 8; ++i2) { run += cs[base + i2]; chunk[i2] = run; }
    part[tid] = run;
  }
  __syncthreads();
#pragma unroll
  for (int off = 1; off < 256; off <<= 1) {
    float v = (tid >= off) ? part[tid - off] : 0.f;
    __syncthreads();
    part[tid] += v;
    __syncthreads();
  }
  const float pofs = (tid > 0) ? part[tid - 1] : 0.f;

  const float inv_k = 1.0f / kf;
  const float c1 = 1.0f + step * kf;
#pragma unroll
  for (int i2 = 0; i2 < 8; ++i2) {
    int jj = base + i2;
    float tau = (chunk[i2] + pofs - c1) * inv_k;
    aout[jj] = f2bf(fmaxf(z[jj] - tau, 0.0f));
  }
}

// ---------------------------------------------------------------------------
extern "C" void kernel_launch(void* const* d_in, const int* in_sizes, int n_in,
                              void* d_out, int out_size, void* d_ws, size_t ws_size,
                              hipStream_t stream) {
  const float* x  = (const float*)d_in[0];
  const float* Wq = (const float*)d_in[1];
  const float* Wk = (const float*)d_in[2];
  const float* Wv = (const float*)d_in[3];
  float* out = (float*)d_out;

  const long long NX = (long long)B_ * S_ * D_;   // 8M
  const long long NW = (long long)H_ * D_;        // 1M
  const long long NP = (long long)B_ * S_ * H_;   // 8M
  const long long NS = (long long)B_ * S_ * S_;   // 16M

  // Workspace layout with aliasing (total 144 MB + 4 B):
  //  [0,64MB):    xs(32) Wqs(4) Wks(4) Wv16(2) V16(16) slack(6)  -> later Sc (fp32, 64MB)
  //  [64,80MB):   x16 (bf16 x, 16MB)                             -> later Vt16 (16MB)
  //  [80,112MB):  Qs (packed, 32MB)                              -> later A16 (bf16 attn, 32MB)
  //  [112,144MB): Ks (packed, 32MB)
  //  [144MB]:     flag
  char* base = (char*)d_ws;
  unsigned int*   xs   = (unsigned int*)(base);
  unsigned int*   Wqs  = (unsigned int*)(base + (32ll << 20));
  unsigned int*   Wks  = (unsigned int*)(base + (36ll << 20));
  unsigned short* Wv16 = (unsigned short*)(base + (40ll << 20));
  unsigned short* V16  = (unsigned short*)(base + (42ll << 20));
  float*          Sc   = (float*)(base);
  unsigned short* x16  = (unsigned short*)(base + (64ll << 20));
  unsigned short* Vt16 = (unsigned short*)(base + (64ll << 20));
  unsigned int*   Qs   = (unsigned int*)(base + (80ll << 20));
  unsigned short* A16  = (unsigned short*)(base + (80ll << 20));
  unsigned int*   Ks   = (unsigned int*)(base + (112ll << 20));
  float*          flag = (float*)(base + (144ll << 20));

  hipMemsetAsync(flag, 0, sizeof(float), stream);
  abs_sum_kernel<<<512, 256, 0, stream>>>(x, NX / 4, flag);

  // pack / convert inputs
  pack_split_kernel<<<(int)(NX / 4 + 255) / 256, 256, 0, stream>>>(x, xs, (int)(NX / 4));
  pack_split_kernel<<<(int)(NW / 4 + 255) / 256, 256, 0, stream>>>(Wq, Wqs, (int)(NW / 4));
  pack_split_kernel<<<(int)(NW / 4 + 255) / 256, 256, 0, stream>>>(Wk, Wks, (int)(NW / 4));
  f2bf_kernel<<<(int)(NX / 4 + 255) / 256, 256, 0, stream>>>(x, x16, (int)(NX / 4));
  f2bf_kernel<<<(int)(NW / 4 + 255) / 256, 256, 0, stream>>>(Wv, Wv16, (int)(NW / 4));

  // Q/K projections, split (packed out); V projection, plain bf16
  {
    dim3 grid(H_ / 128, (B_ * S_) / 128, 1);
    gemm_nt_split<2><<<grid, 256, 0, stream>>>(xs, Wqs, Qs, B_ * S_, H_, D_, 0, 0, 0, 1.0f);
    gemm_nt_split<2><<<grid, 256, 0, stream>>>(xs, Wks, Ks, B_ * S_, H_, D_, 0, 0, 0, 1.0f);
    gemm_nt_mfma<true><<<grid, 256, 0, stream>>>(x16, Wv16, V16, B_ * S_, H_, D_, 0, 0, 0, 1.0f);
  }

  // V^T per batch: [S][H] -> [H][S]   (writes over x16 region; x16 dead)
  {
    dim3 grid(H_ / 32, S_ / 32, B_);
    transpose_bf16<<<grid, dim3(32, 8), 0, stream>>>(V16, Vt16, S_, H_);
  }

  // scores = Q @ K^T / 32, split, fp32 out (writes over xs/W/V16 region; all dead)
  {
    dim3 grid(S_ / 128, S_ / 128, B_);
    gemm_nt_split<0><<<grid, 256, 0, stream>>>(Qs, Ks, Sc, S_, S_, H_,
                                               (long long)S_ * H_, (long long)S_ * H_,
                                               (long long)S_ * S_, 1.0f / 32.0f);
  }

  // attention = sparsemax-or-softmax(scores) -> bf16 (over Qs region; Qs dead)
  attn_row_kernel<<<B_ * S_, 256, 0, stream>>>(Sc, A16, flag);

  // out = attention @ Vt^T, plain bf16 MFMA, fp32 out
  {
    dim3 grid(H_ / 128, S_ / 128, B_);
    gemm_nt_mfma<false><<<grid, 256, 0, stream>>>(A16, Vt16, out, S_, H_, S_,
                                                  (long long)S_ * S_, (long long)H_ * S_,
                                                  (long long)S_ * H_, 1.0f);
  }
}

// Round 5
// 565.602 us; speedup vs baseline: 3.8103x; 1.6259x over previous
//
#include <hip/hip_runtime.h>
#include <math.h>

// Problem constants
#define B_   4
#define S_   2048
#define D_   1024
#define H_   1024
#define NROW 2048
#define TOTX 8388608.0f            // B_*S_*D_ elements of x

typedef short bf16x8 __attribute__((ext_vector_type(8)));
typedef unsigned short u16x8 __attribute__((ext_vector_type(8)));
typedef float f32x4 __attribute__((ext_vector_type(4)));

__device__ __forceinline__ unsigned short f2bf(float f) {
  unsigned int u = __float_as_uint(f);
  unsigned int r = u + 0x7fffu + ((u >> 16) & 1u);   // RNE
  return (unsigned short)(r >> 16);
}
__device__ __forceinline__ float bf2f(unsigned short h) {
  return __uint_as_float(((unsigned int)h) << 16);
}
__device__ __forceinline__ unsigned int packsplit(float v) {
  unsigned short h = f2bf(v);
  unsigned short l = f2bf(v - bf2f(h));
  return (((unsigned int)h) << 16) | l;
}

// ---------------------------------------------------------------------------
// abs-sum reduction for sparsity = mean(|x|)
// ---------------------------------------------------------------------------
__global__ __launch_bounds__(256) void abs_sum_kernel(const float* __restrict__ x,
                                                      long long n4, float* out) {
  long long i0 = (long long)blockIdx.x * blockDim.x + threadIdx.x;
  long long stride = (long long)gridDim.x * blockDim.x;
  float s = 0.f;
  const float4* x4 = (const float4*)x;
  for (long long i = i0; i < n4; i += stride) {
    float4 v = x4[i];
    s += fabsf(v.x) + fabsf(v.y) + fabsf(v.z) + fabsf(v.w);
  }
#pragma unroll
  for (int off = 32; off; off >>= 1) s += __shfl_xor(s, off);
  __shared__ float red[4];
  if ((threadIdx.x & 63) == 0) red[threadIdx.x >> 6] = s;
  __syncthreads();
  if (threadIdx.x == 0) atomicAdd(out, red[0] + red[1] + red[2] + red[3]);
}

// ---------------------------------------------------------------------------
// float -> plain bf16
// ---------------------------------------------------------------------------
__global__ __launch_bounds__(256) void f2bf_kernel(const float* __restrict__ in,
                                                   unsigned short* __restrict__ out,
                                                   int n4) {
  int i = blockIdx.x * 256 + threadIdx.x;
  if (i >= n4) return;
  float4 v = ((const float4*)in)[i];
  ushort4 o;
  o.x = f2bf(v.x); o.y = f2bf(v.y); o.z = f2bf(v.z); o.w = f2bf(v.w);
  ((ushort4*)out)[i] = o;
}

// ---------------------------------------------------------------------------
// float -> packed split bf16 pair (hi<<16 | lo)
// ---------------------------------------------------------------------------
__global__ __launch_bounds__(256) void pack_split_kernel(const float* __restrict__ in,
                                                         unsigned int* __restrict__ out,
                                                         int n4) {
  int i = blockIdx.x * 256 + threadIdx.x;
  if (i >= n4) return;
  float4 v = ((const float4*)in)[i];
  uint4 o;
  o.x = packsplit(v.x); o.y = packsplit(v.y); o.z = packsplit(v.z); o.w = packsplit(v.w);
  ((uint4*)out)[i] = o;
}

// ---------------------------------------------------------------------------
// bf16 transpose per batch: in [R][C] -> out [C][R]
// ---------------------------------------------------------------------------
__global__ __launch_bounds__(256) void transpose_bf16(const unsigned short* __restrict__ in,
                                                      unsigned short* __restrict__ out,
                                                      int R, int C) {
  __shared__ unsigned short t[32][33];
  const int z = blockIdx.z;
  in  += (long long)z * R * C;
  out += (long long)z * R * C;
  const int c0 = blockIdx.x * 32, r0 = blockIdx.y * 32;
#pragma unroll
  for (int i = 0; i < 4; ++i) {
    int r = threadIdx.y + i * 8;
    t[r][threadIdx.x] = in[(long long)(r0 + r) * C + c0 + threadIdx.x];
  }
  __syncthreads();
#pragma unroll
  for (int i = 0; i < 4; ++i) {
    int r = threadIdx.y + i * 8;
    out[(long long)(c0 + r) * R + r0 + threadIdx.x] = t[threadIdx.x][r];
  }
}

// ---------------------------------------------------------------------------
// PLAIN bf16 MFMA GEMM NT (for V projection and PV): C = scale * A B^T
// ---------------------------------------------------------------------------
template <bool OUT_BF16>
__global__ __launch_bounds__(256) void gemm_nt_mfma(const unsigned short* __restrict__ A,
                                                    const unsigned short* __restrict__ B,
                                                    void* __restrict__ Cv,
                                                    int M, int N, int K,
                                                    long long sA, long long sB, long long sC,
                                                    float scale) {
  const int bz = blockIdx.z;
  A += (long long)bz * sA;
  B += (long long)bz * sB;

  __shared__ __align__(16) unsigned short As[128][40];
  __shared__ __align__(16) unsigned short Bs[128][40];

  const int tid = threadIdx.x;
  const int lane = tid & 63;
  const int w = tid >> 6;
  const int wm = (w & 1) << 6;
  const int wn = (w >> 1) << 6;
  const int m0 = blockIdx.y * 128, n0 = blockIdx.x * 128;

  f32x4 acc[4][4] = {};

  const int r0 = tid >> 2;
  const int kq = (tid & 3) * 8;
  const int fm = lane & 15;
  const int fk = (lane >> 4) * 8;

  for (int k0 = 0; k0 < K; k0 += 32) {
    uint4 a0 = *(const uint4*)(A + (long long)(m0 + r0) * K + k0 + kq);
    uint4 a1 = *(const uint4*)(A + (long long)(m0 + r0 + 64) * K + k0 + kq);
    uint4 b0 = *(const uint4*)(B + (long long)(n0 + r0) * K + k0 + kq);
    uint4 b1 = *(const uint4*)(B + (long long)(n0 + r0 + 64) * K + k0 + kq);
    *(uint4*)&As[r0][kq]      = a0;
    *(uint4*)&As[r0 + 64][kq] = a1;
    *(uint4*)&Bs[r0][kq]      = b0;
    *(uint4*)&Bs[r0 + 64][kq] = b1;
    __syncthreads();

    bf16x8 af[4], bfr[4];
#pragma unroll
    for (int mi = 0; mi < 4; ++mi)
      af[mi] = *(const bf16x8*)&As[wm + mi * 16 + fm][fk];
#pragma unroll
    for (int ni = 0; ni < 4; ++ni)
      bfr[ni] = *(const bf16x8*)&Bs[wn + ni * 16 + fm][fk];
#pragma unroll
    for (int mi = 0; mi < 4; ++mi)
#pragma unroll
      for (int ni = 0; ni < 4; ++ni)
        acc[mi][ni] = __builtin_amdgcn_mfma_f32_16x16x32_bf16(af[mi], bfr[ni],
                                                              acc[mi][ni], 0, 0, 0);
    __syncthreads();
  }

  const int cm = (lane >> 4) * 4;
  const int cn = lane & 15;
#pragma unroll
  for (int mi = 0; mi < 4; ++mi)
#pragma unroll
    for (int ni = 0; ni < 4; ++ni) {
#pragma unroll
      for (int r = 0; r < 4; ++r) {
        long long m = m0 + wm + mi * 16 + cm + r;
        long long n = n0 + wn + ni * 16 + cn;
        float v = acc[mi][ni][r] * scale;
        if (OUT_BF16)
          ((unsigned short*)Cv)[(long long)bz * sC + m * N + n] = f2bf(v);
        else
          ((float*)Cv)[(long long)bz * sC + m * N + n] = v;
      }
    }
}

// ---------------------------------------------------------------------------
// SPLIT bf16 MFMA GEMM NT: inputs are packed (hi<<16|lo) per element.
// C = scale * A B^T  via ah*bh + ah*bl + al*bh  (~fp32 accuracy).
// OUT_MODE: 0 = fp32, 2 = packed split.
// ---------------------------------------------------------------------------
template <int OUT_MODE>
__global__ __launch_bounds__(256) void gemm_nt_split(const unsigned int* __restrict__ A,
                                                     const unsigned int* __restrict__ B,
                                                     void* __restrict__ Cv,
                                                     int M, int N, int K,
                                                     long long sA, long long sB, long long sC,
                                                     float scale) {
  const int bz = blockIdx.z;
  A += (long long)bz * sA;
  B += (long long)bz * sB;

  __shared__ __align__(16) unsigned short As_h[128][40];
  __shared__ __align__(16) unsigned short As_l[128][40];
  __shared__ __align__(16) unsigned short Bs_h[128][40];
  __shared__ __align__(16) unsigned short Bs_l[128][40];

  const int tid = threadIdx.x;
  const int lane = tid & 63;
  const int w = tid >> 6;
  const int wm = (w & 1) << 6;
  const int wn = (w >> 1) << 6;
  const int m0 = blockIdx.y * 128, n0 = blockIdx.x * 128;

  f32x4 acc[4][4] = {};

  const int r0 = tid >> 2;
  const int kq = (tid & 3) * 8;
  const int fm = lane & 15;
  const int fk = (lane >> 4) * 8;

  for (int k0 = 0; k0 < K; k0 += 32) {
#pragma unroll
    for (int half = 0; half < 2; ++half) {
      int rr = r0 + half * 64;
      const unsigned int* pa = A + (long long)(m0 + rr) * K + k0 + kq;
      const unsigned int* pb = B + (long long)(n0 + rr) * K + k0 + kq;
      uint4 a0 = *(const uint4*)pa;
      uint4 a1 = *(const uint4*)(pa + 4);
      uint4 b0 = *(const uint4*)pb;
      uint4 b1 = *(const uint4*)(pb + 4);
      u16x8 h, l;
      unsigned int ua[8] = {a0.x, a0.y, a0.z, a0.w, a1.x, a1.y, a1.z, a1.w};
#pragma unroll
      for (int j = 0; j < 8; ++j) { h[j] = (unsigned short)(ua[j] >> 16); l[j] = (unsigned short)ua[j]; }
      *(u16x8*)&As_h[rr][kq] = h;
      *(u16x8*)&As_l[rr][kq] = l;
      unsigned int ub[8] = {b0.x, b0.y, b0.z, b0.w, b1.x, b1.y, b1.z, b1.w};
#pragma unroll
      for (int j = 0; j < 8; ++j) { h[j] = (unsigned short)(ub[j] >> 16); l[j] = (unsigned short)ub[j]; }
      *(u16x8*)&Bs_h[rr][kq] = h;
      *(u16x8*)&Bs_l[rr][kq] = l;
    }
    __syncthreads();

    bf16x8 ah[4], al[4], bh[4], bl[4];
#pragma unroll
    for (int mi = 0; mi < 4; ++mi) {
      ah[mi] = *(const bf16x8*)&As_h[wm + mi * 16 + fm][fk];
      al[mi] = *(const bf16x8*)&As_l[wm + mi * 16 + fm][fk];
    }
#pragma unroll
    for (int ni = 0; ni < 4; ++ni) {
      bh[ni] = *(const bf16x8*)&Bs_h[wn + ni * 16 + fm][fk];
      bl[ni] = *(const bf16x8*)&Bs_l[wn + ni * 16 + fm][fk];
    }
#pragma unroll
    for (int mi = 0; mi < 4; ++mi)
#pragma unroll
      for (int ni = 0; ni < 4; ++ni) {
        acc[mi][ni] = __builtin_amdgcn_mfma_f32_16x16x32_bf16(al[mi], bh[ni], acc[mi][ni], 0, 0, 0);
        acc[mi][ni] = __builtin_amdgcn_mfma_f32_16x16x32_bf16(ah[mi], bl[ni], acc[mi][ni], 0, 0, 0);
        acc[mi][ni] = __builtin_amdgcn_mfma_f32_16x16x32_bf16(ah[mi], bh[ni], acc[mi][ni], 0, 0, 0);
      }
    __syncthreads();
  }

  const int cm = (lane >> 4) * 4;
  const int cn = lane & 15;
#pragma unroll
  for (int mi = 0; mi < 4; ++mi)
#pragma unroll
    for (int ni = 0; ni < 4; ++ni) {
#pragma unroll
      for (int r = 0; r < 4; ++r) {
        long long m = m0 + wm + mi * 16 + cm + r;
        long long n = n0 + wn + ni * 16 + cn;
        float v = acc[mi][ni][r] * scale;
        if (OUT_MODE == 0)
          ((float*)Cv)[(long long)bz * sC + m * N + n] = v;
        else
          ((unsigned int*)Cv)[(long long)bz * sC + m * N + n] = packsplit(v);
      }
    }
}

// ---------------------------------------------------------------------------
// Wave-per-row sparsemax/softmax. Element e = lane*32 + v, 32 values/lane in
// VGPRs. Register bitonic: 45 intra-lane stages (pure VALU) + 21 cross-lane
// stages (shfl_xor). No LDS, no __syncthreads.
// ---------------------------------------------------------------------------
template <int K, int J>
__device__ __forceinline__ void intra_s(float (&r)[32]) {
#pragma unroll
  for (int v = 0; v < 32; ++v)
    if ((v & J) == 0) {
      const int u = v | J;
      const bool dsc = ((v & K) == 0);
      float a = r[v], b = r[u];
      float mx = fmaxf(a, b), mn = fminf(a, b);
      r[v] = dsc ? mx : mn;
      r[u] = dsc ? mn : mx;
    }
}
template <int J>
__device__ __forceinline__ void intra_d(float (&r)[32], bool dsc) {
#pragma unroll
  for (int v = 0; v < 32; ++v)
    if ((v & J) == 0) {
      const int u = v | J;
      float a = r[v], b = r[u];
      float mx = fmaxf(a, b), mn = fminf(a, b);
      r[v] = dsc ? mx : mn;
      r[u] = dsc ? mn : mx;
    }
}
__device__ __forceinline__ void cross_s(float (&r)[32], int lane, int jl, bool dsc) {
  const bool lower = ((lane & jl) == 0);
  const bool tmax = (dsc == lower);
#pragma unroll
  for (int v = 0; v < 32; ++v) {
    float a = r[v];
    float b = __shfl_xor(a, jl, 64);
    float mx = fmaxf(a, b), mn = fminf(a, b);
    r[v] = tmax ? mx : mn;
  }
}

__global__ __launch_bounds__(256) void attn_row_wave(const float* __restrict__ scores,
                                                     unsigned short* __restrict__ attn,
                                                     const float* __restrict__ absSum) {
  const int tid = threadIdx.x;
  const int lane = tid & 63;
  const int row = blockIdx.x * 4 + (tid >> 6);
  const float* rowp = scores + (long long)row * NROW;
  unsigned short* aout = attn + (long long)row * NROW;

  float z[32];
  const float4* rp4 = (const float4*)(rowp + lane * 32);
#pragma unroll
  for (int q = 0; q < 8; ++q) {
    float4 v4 = rp4[q];
    z[q * 4 + 0] = v4.x; z[q * 4 + 1] = v4.y;
    z[q * 4 + 2] = v4.z; z[q * 4 + 3] = v4.w;
  }

  // row max (wave reduce)
  float lm = z[0];
#pragma unroll
  for (int v = 1; v < 32; ++v) lm = fmaxf(lm, z[v]);
#pragma unroll
  for (int off = 32; off; off >>= 1) lm = fmaxf(lm, __shfl_xor(lm, off, 64));

  const bool use_softmax = (absSum[0] * (1.0f / TOTX)) >= 1.0f;

  if (use_softmax) {
    float ls = 0.f;
#pragma unroll
    for (int v = 0; v < 32; ++v) { z[v] = expf(z[v] - lm); ls += z[v]; }
#pragma unroll
    for (int off = 32; off; off >>= 1) ls += __shfl_xor(ls, off, 64);
    float inv = 1.0f / ls;
    ushort4* op = (ushort4*)(aout + lane * 32);
#pragma unroll
    for (int q = 0; q < 8; ++q) {
      ushort4 o;
      o.x = f2bf(z[q * 4 + 0] * inv); o.y = f2bf(z[q * 4 + 1] * inv);
      o.z = f2bf(z[q * 4 + 2] * inv); o.w = f2bf(z[q * 4 + 3] * inv);
      op[q] = o;
    }
    return;
  }

  // ---- sparsemax ----
  float r[32];
  float lsum = 0.f;
#pragma unroll
  for (int v = 0; v < 32; ++v) { z[v] -= lm; r[v] = z[v]; lsum += z[v]; }
#pragma unroll
  for (int off = 32; off; off >>= 1) lsum += __shfl_xor(lsum, off, 64);
  const float step = (lsum - 1.0f) * (1.0f / (float)NROW);

  // bitonic sort descending, e = lane*32 + v
  intra_s<2, 1>(r);
  intra_s<4, 2>(r); intra_s<4, 1>(r);
  intra_s<8, 4>(r); intra_s<8, 2>(r); intra_s<8, 1>(r);
  intra_s<16, 8>(r); intra_s<16, 4>(r); intra_s<16, 2>(r); intra_s<16, 1>(r);
  for (int kl = 1; kl <= 64; kl <<= 1) {
    const bool dsc = ((lane & kl) == 0);
    for (int jl = kl >> 1; jl >= 1; jl >>= 1) cross_s(r, lane, jl, dsc);
    intra_d<16>(r, dsc); intra_d<8>(r, dsc); intra_d<4>(r, dsc);
    intra_d<2>(r, dsc); intra_d<1>(r, dsc);
  }

  // k = count(sorted > step)
  float lcnt = 0.f;
#pragma unroll
  for (int v = 0; v < 32; ++v) lcnt += (r[v] > step) ? 1.0f : 0.0f;
#pragma unroll
  for (int off = 32; off; off >>= 1) lcnt += __shfl_xor(lcnt, off, 64);
  const float kf = lcnt;

  // inclusive cumsum over e: local sequential + wave scan of lane totals
  float run = 0.f;
#pragma unroll
  for (int v = 0; v < 32; ++v) { run += r[v]; r[v] = run; }
  float pre = run;
#pragma unroll
  for (int off = 1; off < 64; off <<= 1) {
    float t = __shfl_up(pre, off, 64);
    if (lane >= off) pre += t;
  }
  pre -= run;  // exclusive prefix of lane totals
#pragma unroll
  for (int v = 0; v < 32; ++v) r[v] += pre;

  const float inv_k = 1.0f / kf;
  const float c1 = 1.0f + step * kf;
  ushort4* op = (ushort4*)(aout + lane * 32);
#pragma unroll
  for (int q = 0; q < 8; ++q) {
    ushort4 o;
    o.x = f2bf(fmaxf(z[q * 4 + 0] - (r[q * 4 + 0] - c1) * inv_k, 0.0f));
    o.y = f2bf(fmaxf(z[q * 4 + 1] - (r[q * 4 + 1] - c1) * inv_k, 0.0f));
    o.z = f2bf(fmaxf(z[q * 4 + 2] - (r[q * 4 + 2] - c1) * inv_k, 0.0f));
    o.w = f2bf(fmaxf(z[q * 4 + 3] - (r[q * 4 + 3] - c1) * inv_k, 0.0f));
    op[q] = o;
  }
}

// ---------------------------------------------------------------------------
extern "C" void kernel_launch(void* const* d_in, const int* in_sizes, int n_in,
                              void* d_out, int out_size, void* d_ws, size_t ws_size,
                              hipStream_t stream) {
  const float* x  = (const float*)d_in[0];
  const float* Wq = (const float*)d_in[1];
  const float* Wk = (const float*)d_in[2];
  const float* Wv = (const float*)d_in[3];
  float* out = (float*)d_out;

  const long long NX = (long long)B_ * S_ * D_;   // 8M
  const long long NW = (long long)H_ * D_;        // 1M

  // Workspace layout with aliasing (total 144 MB + 4 B):
  //  [0,64MB):    xs(32) Wqs(4) Wks(4) Wv16(2) V16(16) slack(6)  -> later Sc (fp32, 64MB)
  //  [64,80MB):   x16 (bf16 x, 16MB)                             -> later Vt16 (16MB)
  //  [80,112MB):  Qs (packed, 32MB)                              -> later A16 (bf16 attn, 32MB)
  //  [112,144MB): Ks (packed, 32MB)
  //  [144MB]:     flag
  char* base = (char*)d_ws;
  unsigned int*   xs   = (unsigned int*)(base);
  unsigned int*   Wqs  = (unsigned int*)(base + (32ll << 20));
  unsigned int*   Wks  = (unsigned int*)(base + (36ll << 20));
  unsigned short* Wv16 = (unsigned short*)(base + (40ll << 20));
  unsigned short* V16  = (unsigned short*)(base + (42ll << 20));
  float*          Sc   = (float*)(base);
  unsigned short* x16  = (unsigned short*)(base + (64ll << 20));
  unsigned short* Vt16 = (unsigned short*)(base + (64ll << 20));
  unsigned int*   Qs   = (unsigned int*)(base + (80ll << 20));
  unsigned short* A16  = (unsigned short*)(base + (80ll << 20));
  unsigned int*   Ks   = (unsigned int*)(base + (112ll << 20));
  float*          flag = (float*)(base + (144ll << 20));

  hipMemsetAsync(flag, 0, sizeof(float), stream);
  abs_sum_kernel<<<512, 256, 0, stream>>>(x, NX / 4, flag);

  // pack / convert inputs
  pack_split_kernel<<<(int)(NX / 4 + 255) / 256, 256, 0, stream>>>(x, xs, (int)(NX / 4));
  pack_split_kernel<<<(int)(NW / 4 + 255) / 256, 256, 0, stream>>>(Wq, Wqs, (int)(NW / 4));
  pack_split_kernel<<<(int)(NW / 4 + 255) / 256, 256, 0, stream>>>(Wk, Wks, (int)(NW / 4));
  f2bf_kernel<<<(int)(NX / 4 + 255) / 256, 256, 0, stream>>>(x, x16, (int)(NX / 4));
  f2bf_kernel<<<(int)(NW / 4 + 255) / 256, 256, 0, stream>>>(Wv, Wv16, (int)(NW / 4));

  // Q/K projections, split (packed out); V projection, plain bf16
  {
    dim3 grid(H_ / 128, (B_ * S_) / 128, 1);
    gemm_nt_split<2><<<grid, 256, 0, stream>>>(xs, Wqs, Qs, B_ * S_, H_, D_, 0, 0, 0, 1.0f);
    gemm_nt_split<2><<<grid, 256, 0, stream>>>(xs, Wks, Ks, B_ * S_, H_, D_, 0, 0, 0, 1.0f);
    gemm_nt_mfma<true><<<grid, 256, 0, stream>>>(x16, Wv16, V16, B_ * S_, H_, D_, 0, 0, 0, 1.0f);
  }

  // V^T per batch: [S][H] -> [H][S]
  {
    dim3 grid(H_ / 32, S_ / 32, B_);
    transpose_bf16<<<grid, dim3(32, 8), 0, stream>>>(V16, Vt16, S_, H_);
  }

  // scores = Q @ K^T / 32, split, fp32 out
  {
    dim3 grid(S_ / 128, S_ / 128, B_);
    gemm_nt_split<0><<<grid, 256, 0, stream>>>(Qs, Ks, Sc, S_, S_, H_,
                                               (long long)S_ * H_, (long long)S_ * H_,
                                               (long long)S_ * S_, 1.0f / 32.0f);
  }

  // attention = sparsemax-or-softmax(scores) -> bf16 (one wave per row)
  attn_row_wave<<<(B_ * S_) / 4, 256, 0, stream>>>(Sc, A16, flag);

  // out = attention @ Vt^T, plain bf16 MFMA, fp32 out
  {
    dim3 grid(H_ / 128, S_ / 128, B_);
    gemm_nt_mfma<false><<<grid, 256, 0, stream>>>(A16, Vt16, out, S_, H_, S_,
                                                  (long long)S_ * S_, (long long)H_ * S_,
                                                  (long long)S_ * H_, 1.0f);
  }
}

// Round 6
// 454.164 us; speedup vs baseline: 4.7452x; 1.2454x over previous
//
#include <hip/hip_runtime.h>
#include <math.h>

// Problem constants
#define B_   4
#define S_   2048
#define D_   1024
#define H_   1024
#define NROW 2048
#define TOTX 8388608.0f            // B_*S_*D_ elements of x

typedef _Float16 f16x8 __attribute__((ext_vector_type(8)));
typedef float f32x4 __attribute__((ext_vector_type(4)));

__device__ __forceinline__ unsigned short f2h(float f) {
  _Float16 h = (_Float16)f;                       // v_cvt_f16_f32, RNE
  return __builtin_bit_cast(unsigned short, h);
}

// ---------------------------------------------------------------------------
// abs-sum reduction for sparsity = mean(|x|)
// ---------------------------------------------------------------------------
__global__ __launch_bounds__(256) void abs_sum_kernel(const float* __restrict__ x,
                                                      long long n4, float* out) {
  long long i0 = (long long)blockIdx.x * blockDim.x + threadIdx.x;
  long long stride = (long long)gridDim.x * blockDim.x;
  float s = 0.f;
  const float4* x4 = (const float4*)x;
  for (long long i = i0; i < n4; i += stride) {
    float4 v = x4[i];
    s += fabsf(v.x) + fabsf(v.y) + fabsf(v.z) + fabsf(v.w);
  }
#pragma unroll
  for (int off = 32; off; off >>= 1) s += __shfl_xor(s, off);
  __shared__ float red[4];
  if ((threadIdx.x & 63) == 0) red[threadIdx.x >> 6] = s;
  __syncthreads();
  if (threadIdx.x == 0) atomicAdd(out, red[0] + red[1] + red[2] + red[3]);
}

// ---------------------------------------------------------------------------
// float -> f16 (bit pattern in ushort), vectorized
// ---------------------------------------------------------------------------
__global__ __launch_bounds__(256) void f2h_kernel(const float* __restrict__ in,
                                                  unsigned short* __restrict__ out,
                                                  int n4) {
  int i = blockIdx.x * 256 + threadIdx.x;
  if (i >= n4) return;
  float4 v = ((const float4*)in)[i];
  ushort4 o;
  o.x = f2h(v.x); o.y = f2h(v.y); o.z = f2h(v.z); o.w = f2h(v.w);
  ((ushort4*)out)[i] = o;
}

// ---------------------------------------------------------------------------
// 16-bit transpose per batch: in [R][C] -> out [C][R]
// ---------------------------------------------------------------------------
__global__ __launch_bounds__(256) void transpose_h16(const unsigned short* __restrict__ in,
                                                     unsigned short* __restrict__ out,
                                                     int R, int C) {
  __shared__ unsigned short t[32][33];
  const int z = blockIdx.z;
  in  += (long long)z * R * C;
  out += (long long)z * R * C;
  const int c0 = blockIdx.x * 32, r0 = blockIdx.y * 32;
#pragma unroll
  for (int i = 0; i < 4; ++i) {
    int r = threadIdx.y + i * 8;
    t[r][threadIdx.x] = in[(long long)(r0 + r) * C + c0 + threadIdx.x];
  }
  __syncthreads();
#pragma unroll
  for (int i = 0; i < 4; ++i) {
    int r = threadIdx.y + i * 8;
    out[(long long)(c0 + r) * R + r0 + threadIdx.x] = t[threadIdx.x][r];
  }
}

// ---------------------------------------------------------------------------
// f16 MFMA GEMM NT: C[m,n] = scale * sum_k A[m,k]*B[n,k]
// A: MxK f16 rm, B: NxK f16 rm. 128x128 tile, BK=32, 256 thr (4 waves),
// each wave 64x64 via 4x4 grid of 16x16x32 MFMAs. fp32 accumulate.
// ---------------------------------------------------------------------------
template <bool OUT_F16>
__global__ __launch_bounds__(256) void gemm_nt_mfma(const unsigned short* __restrict__ A,
                                                    const unsigned short* __restrict__ B,
                                                    void* __restrict__ Cv,
                                                    int M, int N, int K,
                                                    long long sA, long long sB, long long sC,
                                                    float scale) {
  const int bz = blockIdx.z;
  A += (long long)bz * sA;
  B += (long long)bz * sB;

  __shared__ __align__(16) unsigned short As[128][40];  // +8 pad, 80B row stride
  __shared__ __align__(16) unsigned short Bs[128][40];

  const int tid = threadIdx.x;
  const int lane = tid & 63;
  const int w = tid >> 6;
  const int wm = (w & 1) << 6;
  const int wn = (w >> 1) << 6;
  const int m0 = blockIdx.y * 128, n0 = blockIdx.x * 128;

  f32x4 acc[4][4] = {};

  const int r0 = tid >> 2;           // 0..63
  const int kq = (tid & 3) * 8;      // 0,8,16,24
  const int fm = lane & 15;
  const int fk = (lane >> 4) * 8;

  for (int k0 = 0; k0 < K; k0 += 32) {
    uint4 a0 = *(const uint4*)(A + (long long)(m0 + r0) * K + k0 + kq);
    uint4 a1 = *(const uint4*)(A + (long long)(m0 + r0 + 64) * K + k0 + kq);
    uint4 b0 = *(const uint4*)(B + (long long)(n0 + r0) * K + k0 + kq);
    uint4 b1 = *(const uint4*)(B + (long long)(n0 + r0 + 64) * K + k0 + kq);
    *(uint4*)&As[r0][kq]      = a0;
    *(uint4*)&As[r0 + 64][kq] = a1;
    *(uint4*)&Bs[r0][kq]      = b0;
    *(uint4*)&Bs[r0 + 64][kq] = b1;
    __syncthreads();

    f16x8 af[4], bfr[4];
#pragma unroll
    for (int mi = 0; mi < 4; ++mi)
      af[mi] = *(const f16x8*)&As[wm + mi * 16 + fm][fk];
#pragma unroll
    for (int ni = 0; ni < 4; ++ni)
      bfr[ni] = *(const f16x8*)&Bs[wn + ni * 16 + fm][fk];
#pragma unroll
    for (int mi = 0; mi < 4; ++mi)
#pragma unroll
      for (int ni = 0; ni < 4; ++ni)
        acc[mi][ni] = __builtin_amdgcn_mfma_f32_16x16x32_f16(af[mi], bfr[ni],
                                                             acc[mi][ni], 0, 0, 0);
    __syncthreads();
  }

  // epilogue: C/D layout col=lane&15, row=(lane>>4)*4+reg
  const int cm = (lane >> 4) * 4;
  const int cn = lane & 15;
#pragma unroll
  for (int mi = 0; mi < 4; ++mi)
#pragma unroll
    for (int ni = 0; ni < 4; ++ni) {
#pragma unroll
      for (int r = 0; r < 4; ++r) {
        long long m = m0 + wm + mi * 16 + cm + r;
        long long n = n0 + wn + ni * 16 + cn;
        float v = acc[mi][ni][r] * scale;
        if (OUT_F16)
          ((unsigned short*)Cv)[(long long)bz * sC + m * N + n] = f2h(v);
        else
          ((float*)Cv)[(long long)bz * sC + m * N + n] = v;
      }
    }
}

// ---------------------------------------------------------------------------
// Wave-per-row sparsemax/softmax. Element e = lane*32 + v, 32 values/lane in
// VGPRs. Register bitonic: 45 intra-lane stages (pure VALU) + 21 cross-lane
// stages (shfl_xor). No LDS, no __syncthreads. f16 output.
// ---------------------------------------------------------------------------
template <int K, int J>
__device__ __forceinline__ void intra_s(float (&r)[32]) {
#pragma unroll
  for (int v = 0; v < 32; ++v)
    if ((v & J) == 0) {
      const int u = v | J;
      const bool dsc = ((v & K) == 0);
      float a = r[v], b = r[u];
      float mx = fmaxf(a, b), mn = fminf(a, b);
      r[v] = dsc ? mx : mn;
      r[u] = dsc ? mn : mx;
    }
}
template <int J>
__device__ __forceinline__ void intra_d(float (&r)[32], bool dsc) {
#pragma unroll
  for (int v = 0; v < 32; ++v)
    if ((v & J) == 0) {
      const int u = v | J;
      float a = r[v], b = r[u];
      float mx = fmaxf(a, b), mn = fminf(a, b);
      r[v] = dsc ? mx : mn;
      r[u] = dsc ? mn : mx;
    }
}
__device__ __forceinline__ void cross_s(float (&r)[32], int lane, int jl, bool dsc) {
  const bool lower = ((lane & jl) == 0);
  const bool tmax = (dsc == lower);
#pragma unroll
  for (int v = 0; v < 32; ++v) {
    float a = r[v];
    float b = __shfl_xor(a, jl, 64);
    float mx = fmaxf(a, b), mn = fminf(a, b);
    r[v] = tmax ? mx : mn;
  }
}

__global__ __launch_bounds__(256) void attn_row_wave(const float* __restrict__ scores,
                                                     unsigned short* __restrict__ attn,
                                                     const float* __restrict__ absSum) {
  const int tid = threadIdx.x;
  const int lane = tid & 63;
  const int row = blockIdx.x * 4 + (tid >> 6);
  const float* rowp = scores + (long long)row * NROW;
  unsigned short* aout = attn + (long long)row * NROW;

  float z[32];
  const float4* rp4 = (const float4*)(rowp + lane * 32);
#pragma unroll
  for (int q = 0; q < 8; ++q) {
    float4 v4 = rp4[q];
    z[q * 4 + 0] = v4.x; z[q * 4 + 1] = v4.y;
    z[q * 4 + 2] = v4.z; z[q * 4 + 3] = v4.w;
  }

  // row max (wave reduce)
  float lm = z[0];
#pragma unroll
  for (int v = 1; v < 32; ++v) lm = fmaxf(lm, z[v]);
#pragma unroll
  for (int off = 32; off; off >>= 1) lm = fmaxf(lm, __shfl_xor(lm, off, 64));

  const bool use_softmax = (absSum[0] * (1.0f / TOTX)) >= 1.0f;

  if (use_softmax) {
    float ls = 0.f;
#pragma unroll
    for (int v = 0; v < 32; ++v) { z[v] = expf(z[v] - lm); ls += z[v]; }
#pragma unroll
    for (int off = 32; off; off >>= 1) ls += __shfl_xor(ls, off, 64);
    float inv = 1.0f / ls;
    ushort4* op = (ushort4*)(aout + lane * 32);
#pragma unroll
    for (int q = 0; q < 8; ++q) {
      ushort4 o;
      o.x = f2h(z[q * 4 + 0] * inv); o.y = f2h(z[q * 4 + 1] * inv);
      o.z = f2h(z[q * 4 + 2] * inv); o.w = f2h(z[q * 4 + 3] * inv);
      op[q] = o;
    }
    return;
  }

  // ---- sparsemax ----
  float r[32];
  float lsum = 0.f;
#pragma unroll
  for (int v = 0; v < 32; ++v) { z[v] -= lm; r[v] = z[v]; lsum += z[v]; }
#pragma unroll
  for (int off = 32; off; off >>= 1) lsum += __shfl_xor(lsum, off, 64);
  const float step = (lsum - 1.0f) * (1.0f / (float)NROW);

  // bitonic sort descending, e = lane*32 + v
  intra_s<2, 1>(r);
  intra_s<4, 2>(r); intra_s<4, 1>(r);
  intra_s<8, 4>(r); intra_s<8, 2>(r); intra_s<8, 1>(r);
  intra_s<16, 8>(r); intra_s<16, 4>(r); intra_s<16, 2>(r); intra_s<16, 1>(r);
  for (int kl = 1; kl <= 64; kl <<= 1) {
    const bool dsc = ((lane & kl) == 0);
    for (int jl = kl >> 1; jl >= 1; jl >>= 1) cross_s(r, lane, jl, dsc);
    intra_d<16>(r, dsc); intra_d<8>(r, dsc); intra_d<4>(r, dsc);
    intra_d<2>(r, dsc); intra_d<1>(r, dsc);
  }

  // k = count(sorted > step)
  float lcnt = 0.f;
#pragma unroll
  for (int v = 0; v < 32; ++v) lcnt += (r[v] > step) ? 1.0f : 0.0f;
#pragma unroll
  for (int off = 32; off; off >>= 1) lcnt += __shfl_xor(lcnt, off, 64);
  const float kf = lcnt;

  // inclusive cumsum over e: local sequential + wave scan of lane totals
  float run = 0.f;
#pragma unroll
  for (int v = 0; v < 32; ++v) { run += r[v]; r[v] = run; }
  float pre = run;
#pragma unroll
  for (int off = 1; off < 64; off <<= 1) {
    float t = __shfl_up(pre, off, 64);
    if (lane >= off) pre += t;
  }
  pre -= run;  // exclusive prefix of lane totals
#pragma unroll
  for (int v = 0; v < 32; ++v) r[v] += pre;

  const float inv_k = 1.0f / kf;
  const float c1 = 1.0f + step * kf;
  ushort4* op = (ushort4*)(aout + lane * 32);
#pragma unroll
  for (int q = 0; q < 8; ++q) {
    ushort4 o;
    o.x = f2h(fmaxf(z[q * 4 + 0] - (r[q * 4 + 0] - c1) * inv_k, 0.0f));
    o.y = f2h(fmaxf(z[q * 4 + 1] - (r[q * 4 + 1] - c1) * inv_k, 0.0f));
    o.z = f2h(fmaxf(z[q * 4 + 2] - (r[q * 4 + 2] - c1) * inv_k, 0.0f));
    o.w = f2h(fmaxf(z[q * 4 + 3] - (r[q * 4 + 3] - c1) * inv_k, 0.0f));
    op[q] = o;
  }
}

// ---------------------------------------------------------------------------
extern "C" void kernel_launch(void* const* d_in, const int* in_sizes, int n_in,
                              void* d_out, int out_size, void* d_ws, size_t ws_size,
                              hipStream_t stream) {
  const float* x  = (const float*)d_in[0];
  const float* Wq = (const float*)d_in[1];
  const float* Wk = (const float*)d_in[2];
  const float* Wv = (const float*)d_in[3];
  float* out = (float*)d_out;

  const long long NX = (long long)B_ * S_ * D_;   // 8M
  const long long NW = (long long)H_ * D_;        // 1M

  // Workspace layout with aliasing (total 144 MB + 4 B):
  //  [0,64MB):    x16(16) Wq16(2) Wk16(2) Wv16(2) V16(16) slack -> later Sc (fp32, 64MB)
  //  [64,80MB):   Vt16 (16MB, persists to PV)
  //  [80,96MB):   Q16 (16MB, persists to QK^T)
  //  [96,112MB):  K16 (16MB, persists to QK^T)
  //  [112,144MB): A16 (f16 attention, 32MB)
  //  [144MB]:     flag
  char* base = (char*)d_ws;
  unsigned short* x16  = (unsigned short*)(base);
  unsigned short* Wq16 = (unsigned short*)(base + (16ll << 20));
  unsigned short* Wk16 = (unsigned short*)(base + (18ll << 20));
  unsigned short* Wv16 = (unsigned short*)(base + (20ll << 20));
  unsigned short* V16  = (unsigned short*)(base + (22ll << 20));
  float*          Sc   = (float*)(base);
  unsigned short* Vt16 = (unsigned short*)(base + (64ll << 20));
  unsigned short* Q16  = (unsigned short*)(base + (80ll << 20));
  unsigned short* K16  = (unsigned short*)(base + (96ll << 20));
  unsigned short* A16  = (unsigned short*)(base + (112ll << 20));
  float*          flag = (float*)(base + (144ll << 20));

  hipMemsetAsync(flag, 0, sizeof(float), stream);
  abs_sum_kernel<<<512, 256, 0, stream>>>(x, NX / 4, flag);

  // f16 conversions
  f2h_kernel<<<(int)(NX / 4 + 255) / 256, 256, 0, stream>>>(x, x16, (int)(NX / 4));
  f2h_kernel<<<(int)(NW / 4 + 255) / 256, 256, 0, stream>>>(Wq, Wq16, (int)(NW / 4));
  f2h_kernel<<<(int)(NW / 4 + 255) / 256, 256, 0, stream>>>(Wk, Wk16, (int)(NW / 4));
  f2h_kernel<<<(int)(NW / 4 + 255) / 256, 256, 0, stream>>>(Wv, Wv16, (int)(NW / 4));

  // Projections: Q/K/V = x @ W^T  (M=8192, N=1024, K=1024), f16 out
  {
    dim3 grid(H_ / 128, (B_ * S_) / 128, 1);
    gemm_nt_mfma<true><<<grid, 256, 0, stream>>>(x16, Wq16, Q16, B_ * S_, H_, D_, 0, 0, 0, 1.0f);
    gemm_nt_mfma<true><<<grid, 256, 0, stream>>>(x16, Wk16, K16, B_ * S_, H_, D_, 0, 0, 0, 1.0f);
    gemm_nt_mfma<true><<<grid, 256, 0, stream>>>(x16, Wv16, V16, B_ * S_, H_, D_, 0, 0, 0, 1.0f);
  }

  // V^T per batch: [S][H] -> [H][S]
  {
    dim3 grid(H_ / 32, S_ / 32, B_);
    transpose_h16<<<grid, dim3(32, 8), 0, stream>>>(V16, Vt16, S_, H_);
  }

  // scores = Q @ K^T / 32 (batched, fp32 out; overwrites x16/W/V16 — all dead)
  {
    dim3 grid(S_ / 128, S_ / 128, B_);
    gemm_nt_mfma<false><<<grid, 256, 0, stream>>>(Q16, K16, Sc, S_, S_, H_,
                                                  (long long)S_ * H_, (long long)S_ * H_,
                                                  (long long)S_ * S_, 1.0f / 32.0f);
  }

  // attention = sparsemax-or-softmax(scores) -> f16 (one wave per row)
  attn_row_wave<<<(B_ * S_) / 4, 256, 0, stream>>>(Sc, A16, flag);

  // out = attention @ Vt^T, f16 MFMA, fp32 out
  {
    dim3 grid(H_ / 128, S_ / 128, B_);
    gemm_nt_mfma<false><<<grid, 256, 0, stream>>>(A16, Vt16, out, S_, H_, S_,
                                                  (long long)S_ * S_, (long long)H_ * S_,
                                                  (long long)S_ * H_, 1.0f);
  }
}

// Round 7
// 443.779 us; speedup vs baseline: 4.8562x; 1.0234x over previous
//
#include <hip/hip_runtime.h>
#include <math.h>

// Problem constants
#define B_   4
#define S_   2048
#define D_   1024
#define H_   1024
#define NROW 2048
#define TOTX 8388608.0f            // B_*S_*D_ elements of x

typedef _Float16 f16x8 __attribute__((ext_vector_type(8)));
typedef float f32x4 __attribute__((ext_vector_type(4)));

__device__ __forceinline__ unsigned short f2h(float f) {
  _Float16 h = (_Float16)f;                       // v_cvt_f16_f32, RNE
  return __builtin_bit_cast(unsigned short, h);
}

// async global->LDS, 16B per lane, lands at ldsbase + lane*16
#define GLD16(gp, lp)                                                            \
  __builtin_amdgcn_global_load_lds(                                              \
      (__attribute__((address_space(1))) void*)(gp),                             \
      (__attribute__((address_space(3))) void*)(lp), 16, 0, 0)

// ---------------------------------------------------------------------------
// abs-sum reduction for sparsity = mean(|x|)
// ---------------------------------------------------------------------------
__global__ __launch_bounds__(256) void abs_sum_kernel(const float* __restrict__ x,
                                                      long long n4, float* out) {
  long long i0 = (long long)blockIdx.x * blockDim.x + threadIdx.x;
  long long stride = (long long)gridDim.x * blockDim.x;
  float s = 0.f;
  const float4* x4 = (const float4*)x;
  for (long long i = i0; i < n4; i += stride) {
    float4 v = x4[i];
    s += fabsf(v.x) + fabsf(v.y) + fabsf(v.z) + fabsf(v.w);
  }
#pragma unroll
  for (int off = 32; off; off >>= 1) s += __shfl_xor(s, off);
  __shared__ float red[4];
  if ((threadIdx.x & 63) == 0) red[threadIdx.x >> 6] = s;
  __syncthreads();
  if (threadIdx.x == 0) atomicAdd(out, red[0] + red[1] + red[2] + red[3]);
}

// ---------------------------------------------------------------------------
// float -> f16 (bit pattern in ushort), vectorized
// ---------------------------------------------------------------------------
__global__ __launch_bounds__(256) void f2h_kernel(const float* __restrict__ in,
                                                  unsigned short* __restrict__ out,
                                                  int n4) {
  int i = blockIdx.x * 256 + threadIdx.x;
  if (i >= n4) return;
  float4 v = ((const float4*)in)[i];
  ushort4 o;
  o.x = f2h(v.x); o.y = f2h(v.y); o.z = f2h(v.z); o.w = f2h(v.w);
  ((ushort4*)out)[i] = o;
}

// ---------------------------------------------------------------------------
// 16-bit transpose per batch: in [R][C] -> out [C][R]
// ---------------------------------------------------------------------------
__global__ __launch_bounds__(256) void transpose_h16(const unsigned short* __restrict__ in,
                                                     unsigned short* __restrict__ out,
                                                     int R, int C) {
  __shared__ unsigned short t[32][33];
  const int z = blockIdx.z;
  in  += (long long)z * R * C;
  out += (long long)z * R * C;
  const int c0 = blockIdx.x * 32, r0 = blockIdx.y * 32;
#pragma unroll
  for (int i = 0; i < 4; ++i) {
    int r = threadIdx.y + i * 8;
    t[r][threadIdx.x] = in[(long long)(r0 + r) * C + c0 + threadIdx.x];
  }
  __syncthreads();
#pragma unroll
  for (int i = 0; i < 4; ++i) {
    int r = threadIdx.y + i * 8;
    out[(long long)(c0 + r) * R + r0 + threadIdx.x] = t[threadIdx.x][r];
  }
}

// ---------------------------------------------------------------------------
// f16 MFMA GEMM NT (m97 structure): C[m,n] = scale * sum_k A[m,k]*B[n,k]
// 128x128 tile, BK=32, 256 thr (4 waves), 4x4 16x16x32 MFMAs per wave.
// Staging: global_load_lds 16B/lane into LINEAR LDS with XOR chunk swizzle
// (chunk ^= (row>>1)&3) so ds_read_b128 fragment reads are 2-way (free).
// ---------------------------------------------------------------------------
template <bool OUT_F16>
__global__ __launch_bounds__(256) void gemm_nt_mfma(const unsigned short* __restrict__ A,
                                                    const unsigned short* __restrict__ B,
                                                    void* __restrict__ Cv,
                                                    int M, int N, int K,
                                                    long long sA, long long sB, long long sC,
                                                    float scale) {
  const int bz = blockIdx.z;
  A += (long long)bz * sA;
  B += (long long)bz * sB;

  __shared__ __align__(16) unsigned short As[128 * 32];   // linear, 64B row stride
  __shared__ __align__(16) unsigned short Bs[128 * 32];

  const int tid = threadIdx.x;
  const int lane = tid & 63;
  const int w = tid >> 6;
  const int wm = (w & 1) << 6;
  const int wn = (w >> 1) << 6;
  const int m0 = blockIdx.y * 128, n0 = blockIdx.x * 128;

  f32x4 acc[4][4] = {};

  // staging: lane l of wave w fetches row (w*16 + l/4), global chunk c = (l&3)^((l>>3)&3)
  const int srow = tid >> 2;                               // = w*16 + (lane>>2)
  const int scol = ((lane & 3) ^ ((lane >> 3) & 3)) * 8;   // f16 elems
  unsigned short* aL0 = &As[(w * 16) * 32];
  unsigned short* aL1 = &As[(64 + w * 16) * 32];
  unsigned short* bL0 = &Bs[(w * 16) * 32];
  unsigned short* bL1 = &Bs[(64 + w * 16) * 32];

  // fragment read addresses (loop-invariant): row = wm+mi*16+fm, col chunk
  // fkc = lane>>4 stored at chunk fkc ^ ((row>>1)&3); (row>>1)&3 == (lane>>1)&3
  const int fm = lane & 15;
  const int col8 = (((lane >> 4) ^ ((lane >> 1) & 3)) * 8);
  const unsigned short* afp[4];
  const unsigned short* bfp[4];
#pragma unroll
  for (int mi = 0; mi < 4; ++mi) {
    afp[mi] = &As[(wm + mi * 16 + fm) * 32 + col8];
    bfp[mi] = &Bs[(wn + mi * 16 + fm) * 32 + col8];
  }

  const unsigned short* gA0 = A + (long long)(m0 + srow) * K + scol;
  const unsigned short* gA1 = A + (long long)(m0 + 64 + srow) * K + scol;
  const unsigned short* gB0 = B + (long long)(n0 + srow) * K + scol;
  const unsigned short* gB1 = B + (long long)(n0 + 64 + srow) * K + scol;

  for (int k0 = 0; k0 < K; k0 += 32) {
    GLD16(gA0 + k0, aL0);
    GLD16(gA1 + k0, aL1);
    GLD16(gB0 + k0, bL0);
    GLD16(gB1 + k0, bL1);
    __syncthreads();

    f16x8 af[4], bfr[4];
#pragma unroll
    for (int mi = 0; mi < 4; ++mi) af[mi] = *(const f16x8*)afp[mi];
#pragma unroll
    for (int ni = 0; ni < 4; ++ni) bfr[ni] = *(const f16x8*)bfp[ni];
#pragma unroll
    for (int mi = 0; mi < 4; ++mi)
#pragma unroll
      for (int ni = 0; ni < 4; ++ni)
        acc[mi][ni] = __builtin_amdgcn_mfma_f32_16x16x32_f16(af[mi], bfr[ni],
                                                             acc[mi][ni], 0, 0, 0);
    __syncthreads();
  }

  // epilogue: C/D layout col=lane&15, row=(lane>>4)*4+reg
  const int cm = (lane >> 4) * 4;
  const int cn = lane & 15;
#pragma unroll
  for (int mi = 0; mi < 4; ++mi)
#pragma unroll
    for (int ni = 0; ni < 4; ++ni) {
#pragma unroll
      for (int r = 0; r < 4; ++r) {
        long long m = m0 + wm + mi * 16 + cm + r;
        long long n = n0 + wn + ni * 16 + cn;
        float v = acc[mi][ni][r] * scale;
        if (OUT_F16)
          ((unsigned short*)Cv)[(long long)bz * sC + m * N + n] = f2h(v);
        else
          ((float*)Cv)[(long long)bz * sC + m * N + n] = v;
      }
    }
}

// ---------------------------------------------------------------------------
// Wave-per-row sparsemax/softmax. Element e = lane*32 + v, 32 values/lane in
// VGPRs. Register bitonic; no LDS, no __syncthreads. f16 output.
// ---------------------------------------------------------------------------
template <int K, int J>
__device__ __forceinline__ void intra_s(float (&r)[32]) {
#pragma unroll
  for (int v = 0; v < 32; ++v)
    if ((v & J) == 0) {
      const int u = v | J;
      const bool dsc = ((v & K) == 0);
      float a = r[v], b = r[u];
      float mx = fmaxf(a, b), mn = fminf(a, b);
      r[v] = dsc ? mx : mn;
      r[u] = dsc ? mn : mx;
    }
}
template <int J>
__device__ __forceinline__ void intra_d(float (&r)[32], bool dsc) {
#pragma unroll
  for (int v = 0; v < 32; ++v)
    if ((v & J) == 0) {
      const int u = v | J;
      float a = r[v], b = r[u];
      float mx = fmaxf(a, b), mn = fminf(a, b);
      r[v] = dsc ? mx : mn;
      r[u] = dsc ? mn : mx;
    }
}
__device__ __forceinline__ void cross_s(float (&r)[32], int lane, int jl, bool dsc) {
  const bool lower = ((lane & jl) == 0);
  const bool tmax = (dsc == lower);
#pragma unroll
  for (int v = 0; v < 32; ++v) {
    float a = r[v];
    float b = __shfl_xor(a, jl, 64);
    float mx = fmaxf(a, b), mn = fminf(a, b);
    r[v] = tmax ? mx : mn;
  }
}

__global__ __launch_bounds__(256) void attn_row_wave(const float* __restrict__ scores,
                                                     unsigned short* __restrict__ attn,
                                                     const float* __restrict__ absSum) {
  const int tid = threadIdx.x;
  const int lane = tid & 63;
  const int row = blockIdx.x * 4 + (tid >> 6);
  const float* rowp = scores + (long long)row * NROW;
  unsigned short* aout = attn + (long long)row * NROW;

  float z[32];
  const float4* rp4 = (const float4*)(rowp + lane * 32);
#pragma unroll
  for (int q = 0; q < 8; ++q) {
    float4 v4 = rp4[q];
    z[q * 4 + 0] = v4.x; z[q * 4 + 1] = v4.y;
    z[q * 4 + 2] = v4.z; z[q * 4 + 3] = v4.w;
  }

  // row max (wave reduce)
  float lm = z[0];
#pragma unroll
  for (int v = 1; v < 32; ++v) lm = fmaxf(lm, z[v]);
#pragma unroll
  for (int off = 32; off; off >>= 1) lm = fmaxf(lm, __shfl_xor(lm, off, 64));

  const bool use_softmax = (absSum[0] * (1.0f / TOTX)) >= 1.0f;

  if (use_softmax) {
    float ls = 0.f;
#pragma unroll
    for (int v = 0; v < 32; ++v) { z[v] = expf(z[v] - lm); ls += z[v]; }
#pragma unroll
    for (int off = 32; off; off >>= 1) ls += __shfl_xor(ls, off, 64);
    float inv = 1.0f / ls;
    ushort4* op = (ushort4*)(aout + lane * 32);
#pragma unroll
    for (int q = 0; q < 8; ++q) {
      ushort4 o;
      o.x = f2h(z[q * 4 + 0] * inv); o.y = f2h(z[q * 4 + 1] * inv);
      o.z = f2h(z[q * 4 + 2] * inv); o.w = f2h(z[q * 4 + 3] * inv);
      op[q] = o;
    }
    return;
  }

  // ---- sparsemax ----
  float r[32];
  float lsum = 0.f;
#pragma unroll
  for (int v = 0; v < 32; ++v) { z[v] -= lm; r[v] = z[v]; lsum += z[v]; }
#pragma unroll
  for (int off = 32; off; off >>= 1) lsum += __shfl_xor(lsum, off, 64);
  const float step = (lsum - 1.0f) * (1.0f / (float)NROW);

  // bitonic sort descending, e = lane*32 + v
  intra_s<2, 1>(r);
  intra_s<4, 2>(r); intra_s<4, 1>(r);
  intra_s<8, 4>(r); intra_s<8, 2>(r); intra_s<8, 1>(r);
  intra_s<16, 8>(r); intra_s<16, 4>(r); intra_s<16, 2>(r); intra_s<16, 1>(r);
  for (int kl = 1; kl <= 64; kl <<= 1) {
    const bool dsc = ((lane & kl) == 0);
    for (int jl = kl >> 1; jl >= 1; jl >>= 1) cross_s(r, lane, jl, dsc);
    intra_d<16>(r, dsc); intra_d<8>(r, dsc); intra_d<4>(r, dsc);
    intra_d<2>(r, dsc); intra_d<1>(r, dsc);
  }

  // k = count(sorted > step)
  float lcnt = 0.f;
#pragma unroll
  for (int v = 0; v < 32; ++v) lcnt += (r[v] > step) ? 1.0f : 0.0f;
#pragma unroll
  for (int off = 32; off; off >>= 1) lcnt += __shfl_xor(lcnt, off, 64);
  const float kf = lcnt;

  // inclusive cumsum over e: local sequential + wave scan of lane totals
  float run = 0.f;
#pragma unroll
  for (int v = 0; v < 32; ++v) { run += r[v]; r[v] = run; }
  float pre = run;
#pragma unroll
  for (int off = 1; off < 64; off <<= 1) {
    float t = __shfl_up(pre, off, 64);
    if (lane >= off) pre += t;
  }
  pre -= run;  // exclusive prefix of lane totals
#pragma unroll
  for (int v = 0; v < 32; ++v) r[v] += pre;

  const float inv_k = 1.0f / kf;
  const float c1 = 1.0f + step * kf;
  ushort4* op = (ushort4*)(aout + lane * 32);
#pragma unroll
  for (int q = 0; q < 8; ++q) {
    ushort4 o;
    o.x = f2h(fmaxf(z[q * 4 + 0] - (r[q * 4 + 0] - c1) * inv_k, 0.0f));
    o.y = f2h(fmaxf(z[q * 4 + 1] - (r[q * 4 + 1] - c1) * inv_k, 0.0f));
    o.z = f2h(fmaxf(z[q * 4 + 2] - (r[q * 4 + 2] - c1) * inv_k, 0.0f));
    o.w = f2h(fmaxf(z[q * 4 + 3] - (r[q * 4 + 3] - c1) * inv_k, 0.0f));
    op[q] = o;
  }
}

// ---------------------------------------------------------------------------
extern "C" void kernel_launch(void* const* d_in, const int* in_sizes, int n_in,
                              void* d_out, int out_size, void* d_ws, size_t ws_size,
                              hipStream_t stream) {
  const float* x  = (const float*)d_in[0];
  const float* Wq = (const float*)d_in[1];
  const float* Wk = (const float*)d_in[2];
  const float* Wv = (const float*)d_in[3];
  float* out = (float*)d_out;

  const long long NX = (long long)B_ * S_ * D_;   // 8M
  const long long NW = (long long)H_ * D_;        // 1M

  // Workspace layout with aliasing (total 144 MB + 4 B):
  //  [0,64MB):    x16(16) Wq16(2) Wk16(2) Wv16(2) V16(16) slack -> later Sc (fp32, 64MB)
  //  [64,80MB):   Vt16 (16MB, persists to PV)
  //  [80,96MB):   Q16 (16MB)   [96,112MB): K16 (16MB)
  //  [112,144MB): A16 (f16 attention, 32MB)
  //  [144MB]:     flag
  char* base = (char*)d_ws;
  unsigned short* x16  = (unsigned short*)(base);
  unsigned short* Wq16 = (unsigned short*)(base + (16ll << 20));
  unsigned short* Wk16 = (unsigned short*)(base + (18ll << 20));
  unsigned short* Wv16 = (unsigned short*)(base + (20ll << 20));
  unsigned short* V16  = (unsigned short*)(base + (22ll << 20));
  float*          Sc   = (float*)(base);
  unsigned short* Vt16 = (unsigned short*)(base + (64ll << 20));
  unsigned short* Q16  = (unsigned short*)(base + (80ll << 20));
  unsigned short* K16  = (unsigned short*)(base + (96ll << 20));
  unsigned short* A16  = (unsigned short*)(base + (112ll << 20));
  float*          flag = (float*)(base + (144ll << 20));

  hipMemsetAsync(flag, 0, sizeof(float), stream);
  abs_sum_kernel<<<512, 256, 0, stream>>>(x, NX / 4, flag);

  // f16 conversions
  f2h_kernel<<<(int)(NX / 4 + 255) / 256, 256, 0, stream>>>(x, x16, (int)(NX / 4));
  f2h_kernel<<<(int)(NW / 4 + 255) / 256, 256, 0, stream>>>(Wq, Wq16, (int)(NW / 4));
  f2h_kernel<<<(int)(NW / 4 + 255) / 256, 256, 0, stream>>>(Wk, Wk16, (int)(NW / 4));
  f2h_kernel<<<(int)(NW / 4 + 255) / 256, 256, 0, stream>>>(Wv, Wv16, (int)(NW / 4));

  // Projections: Q/K/V = x @ W^T  (M=8192, N=1024, K=1024), f16 out
  {
    dim3 grid(H_ / 128, (B_ * S_) / 128, 1);
    gemm_nt_mfma<true><<<grid, 256, 0, stream>>>(x16, Wq16, Q16, B_ * S_, H_, D_, 0, 0, 0, 1.0f);
    gemm_nt_mfma<true><<<grid, 256, 0, stream>>>(x16, Wk16, K16, B_ * S_, H_, D_, 0, 0, 0, 1.0f);
    gemm_nt_mfma<true><<<grid, 256, 0, stream>>>(x16, Wv16, V16, B_ * S_, H_, D_, 0, 0, 0, 1.0f);
  }

  // V^T per batch: [S][H] -> [H][S]
  {
    dim3 grid(H_ / 32, S_ / 32, B_);
    transpose_h16<<<grid, dim3(32, 8), 0, stream>>>(V16, Vt16, S_, H_);
  }

  // scores = Q @ K^T / 32 (batched, fp32 out; overwrites x16/W/V16 — all dead)
  {
    dim3 grid(S_ / 128, S_ / 128, B_);
    gemm_nt_mfma<false><<<grid, 256, 0, stream>>>(Q16, K16, Sc, S_, S_, H_,
                                                  (long long)S_ * H_, (long long)S_ * H_,
                                                  (long long)S_ * S_, 1.0f / 32.0f);
  }

  // attention = sparsemax-or-softmax(scores) -> f16 (one wave per row)
  attn_row_wave<<<(B_ * S_) / 4, 256, 0, stream>>>(Sc, A16, flag);

  // out = attention @ Vt^T, f16 MFMA, fp32 out
  {
    dim3 grid(H_ / 128, S_ / 128, B_);
    gemm_nt_mfma<false><<<grid, 256, 0, stream>>>(A16, Vt16, out, S_, H_, S_,
                                                  (long long)S_ * S_, (long long)H_ * S_,
                                                  (long long)S_ * H_, 1.0f);
  }
}